// Round 7
// baseline (110.758 us; speedup 1.0000x reference)
//
#include <hip/hip_runtime.h>
#include <hip/hip_bf16.h>

// Problem constants (match reference)
#define B_   8
#define NQ_  64     // N_CANDS
#define CTX_ 512    // CTX_LEN
#define DC_  512    // CONTEXT_SIZE
#define DQ_  512    // QUERY_SIZE
#define H_   256    // HIDDEN
#define EPS_ 1e-5f

using short8  = __attribute__((ext_vector_type(8))) short;  // 8 bf16 (4 VGPRs)
using floatx4 = __attribute__((ext_vector_type(4))) float;  // MFMA acc

// 2 fp32 -> packed bf16x2 via v_cvt_pk_bf16_f32 (single instruction on gfx950)
__device__ __forceinline__ unsigned pk2(float x, float y) {
    union { __hip_bfloat162 h; unsigned u; } c;
    c.h = __float22bfloat162_rn(make_float2(x, y));
    return c.u;
}
// 8 fp32 (two float4) -> 16B packed bf16
__device__ __forceinline__ uint4 cvt8u(float4 a, float4 b) {
    uint4 r;
    r.x = pk2(a.x, a.y); r.y = pk2(a.z, a.w);
    r.z = pk2(b.x, b.y); r.w = pk2(b.z, b.w);
    return r;
}

// ---------------------------------------------------------------------------
// Kernel 1 (unchanged from R6): both input GEMMs via bf16 MFMA, LDS-staged
// with register prefetch. Epilogue: Ec = exp(2*(acc+bias)), Eq = exp(2*acc)
// (factored-exp form: tanh(x) = 1 - 2/(e^{2x}+1), e^{2(rc+rq)} = Ec*Eq).
// Tile 32Mx64N, BK=64; grid 144x4 = 576 blocks (2.25/CU) for latency hiding.
// ---------------------------------------------------------------------------
__global__ __launch_bounds__(256) void gemm_exp(
    const float* __restrict__ ctx, const float* __restrict__ query,
    const float* __restrict__ W_c, const float* __restrict__ b_c,
    const float* __restrict__ W_q,
    float* __restrict__ Ec, float* __restrict__ Eq)
{
    __shared__ unsigned short As[32][72];   // 32 rows x 64 bf16 (+8 pad)
    __shared__ unsigned short Bs[64][72];   // 64 rows x 64 bf16 (+8 pad)

    const int rt = blockIdx.x;     // 0..143 (128 ctx + 16 query row-tiles)
    const int ct = blockIdx.y;     // 0..3

    const float* A; const float* W; const float* bias; float* outp; int row0;
    if (rt < 128) { A = ctx;   W = W_c; bias = b_c;     outp = Ec; row0 = rt * 32; }
    else          { A = query; W = W_q; bias = nullptr; outp = Eq; row0 = (rt - 128) * 32; }

    const int col0 = ct * 64;
    const int t    = threadIdx.x;
    const int wave = t >> 6;
    const int lane = t & 63;
    const int m  = lane & 15;
    const int kq = lane >> 4;
    const int mh = wave >> 1;      // M-half: rows mh*16..+16
    const int nh = wave & 1;       // N-half: cols nh*32..+32

    const int sr = t >> 3, ss = t & 7;
    const float* gA  = A + (size_t)(row0 + sr) * 512 + ss * 8;
    const float* gB0 = W + (size_t)(col0 + sr) * 512 + ss * 8;
    const float* gB1 = W + (size_t)(col0 + 32 + sr) * 512 + ss * 8;
    unsigned short* lA  = &As[sr][ss * 8];
    unsigned short* lB0 = &Bs[sr][ss * 8];
    unsigned short* lB1 = &Bs[32 + sr][ss * 8];

    floatx4 acc[2] = {};
    float4 pA0, pA1, pB00, pB01, pB10, pB11;

    pA0  = *(const float4*)(gA);       pA1  = *(const float4*)(gA + 4);
    pB00 = *(const float4*)(gB0);      pB01 = *(const float4*)(gB0 + 4);
    pB10 = *(const float4*)(gB1);      pB11 = *(const float4*)(gB1 + 4);

    for (int s = 0; s < 8; ++s) {
        __syncthreads();
        *(uint4*)lA  = cvt8u(pA0, pA1);
        *(uint4*)lB0 = cvt8u(pB00, pB01);
        *(uint4*)lB1 = cvt8u(pB10, pB11);
        __syncthreads();

        if (s < 7) {
            const int k = (s + 1) * 64;
            pA0  = *(const float4*)(gA + k);   pA1  = *(const float4*)(gA + k + 4);
            pB00 = *(const float4*)(gB0 + k);  pB01 = *(const float4*)(gB0 + k + 4);
            pB10 = *(const float4*)(gB1 + k);  pB11 = *(const float4*)(gB1 + k + 4);
        }

        #pragma unroll
        for (int kc = 0; kc < 2; ++kc) {
            short8 af = *(const short8*)&As[mh * 16 + m][kc * 32 + kq * 8];
            short8 b0 = *(const short8*)&Bs[nh * 32 +      m][kc * 32 + kq * 8];
            short8 b1 = *(const short8*)&Bs[nh * 32 + 16 + m][kc * 32 + kq * 8];
            acc[0] = __builtin_amdgcn_mfma_f32_16x16x32_bf16(af, b0, acc[0], 0, 0, 0);
            acc[1] = __builtin_amdgcn_mfma_f32_16x16x32_bf16(af, b1, acc[1], 0, 0, 0);
        }
    }

    #pragma unroll
    for (int j = 0; j < 2; ++j) {
        const int col = col0 + nh * 32 + j * 16 + m;
        const float bb = bias ? bias[col] : 0.f;
        #pragma unroll
        for (int i = 0; i < 4; ++i) {
            const int row = row0 + mh * 16 + kq * 4 + i;
            outp[(size_t)row * H_ + col] = __expf(2.f * (acc[j][i] + bb));
        }
    }
}

// ---------------------------------------------------------------------------
// Kernel 2: scoring. Grid 512 = b(8) x ctile(8: 64c) x qgroup(8: 8q).
// Lane owns one c; wave owns 2 q. Q-side (Eq) and W_o values are read from
// GLOBAL with wave-uniform indices (readfirstlane) -> scalar s_load_dwordx4
// on the SMEM pipe, keeping the LDS pipe for the per-lane Ec reads only.
//  logit = b_o + Sum(W_o) - 2*sum_h W_o[h]/(Ec[c,h]*Eq[q,h]+1)
// Writes e = mask*exp(logit) to eout[q][c] AND transposed eoutT[(b,qg)][c][8].
// ---------------------------------------------------------------------------
__global__ __launch_bounds__(256) void score_kernel(
    const float* __restrict__ Ec,    // B*CTX*H
    const float* __restrict__ Eqm,   // B*NQ*H
    const float* __restrict__ W_o,   // H
    const float* __restrict__ b_o_p, // scalar
    const float* __restrict__ mask,  // B*CTX
    float* __restrict__ eout,        // B*NQ*CTX
    float* __restrict__ eoutT)       // (B*8qg)*CTX*8
{
    __shared__ float ecs[64][68];    // 64c x 64h chunk, stride-68 pad
    __shared__ float redS[4];

    const int blk = blockIdx.x;
    const int b  = blk & 7;          // XCD swizzle
    const int ctile = (blk >> 3) & 7;
    const int qg = blk >> 6;
    const int t  = threadIdx.x;

    // Sum(W_o): coalesced load + butterfly (once)
    float S = W_o[t];
    #pragma unroll
    for (int k = 1; k < 64; k <<= 1) S += __shfl_xor(S, k);
    if ((t & 63) == 0) redS[t >> 6] = S;

    const int cl = t & 63;           // lane's c within tile
    const int qi = __builtin_amdgcn_readfirstlane(t >> 6);  // wave's q-pair (uniform)
    const int c0 = ctile * 64;
    const float* ec_tile = Ec + (size_t)(b * CTX_ + c0) * H_;
    const int sr = t >> 2, sseg = (t & 3) * 16;             // staging map
    const float* ssrc = ec_tile + (size_t)sr * H_ + sseg;
    const float* eqa = Eqm + (size_t)(b * NQ_ + qg * 8 + qi * 2) * H_;  // uniform ptr
    const float* eqc = eqa + H_;                                         // uniform ptr

    float s0 = 0.f, s1 = 0.f;
    for (int hb = 0; hb < 4; ++hb) {
        float4 v0 = *(const float4*)(ssrc + hb * 64);
        float4 v1 = *(const float4*)(ssrc + hb * 64 + 4);
        float4 v2 = *(const float4*)(ssrc + hb * 64 + 8);
        float4 v3 = *(const float4*)(ssrc + hb * 64 + 12);
        __syncthreads();             // prior chunk's compute done (also covers redS)
        float* dst = &ecs[sr][sseg];
        *(float4*)(dst)     = v0; *(float4*)(dst + 4)  = v1;
        *(float4*)(dst + 8) = v2; *(float4*)(dst + 12) = v3;
        __syncthreads();
        const int ho = hb * 64;
        #pragma unroll
        for (int h4 = 0; h4 < 16; ++h4) {
            float4 ea = *(const float4*)&ecs[cl][h4 * 4];        // LDS, per-lane
            float4 qa = *(const float4*)(eqa + ho + h4 * 4);     // s_load (uniform)
            float4 qc = *(const float4*)(eqc + ho + h4 * 4);     // s_load (uniform)
            float4 w4 = *(const float4*)(W_o + ho + h4 * 4);     // s_load (uniform)
            s0 += w4.x * __builtin_amdgcn_rcpf(ea.x * qa.x + 1.f);
            s0 += w4.y * __builtin_amdgcn_rcpf(ea.y * qa.y + 1.f);
            s0 += w4.z * __builtin_amdgcn_rcpf(ea.z * qa.z + 1.f);
            s0 += w4.w * __builtin_amdgcn_rcpf(ea.w * qa.w + 1.f);
            s1 += w4.x * __builtin_amdgcn_rcpf(ea.x * qc.x + 1.f);
            s1 += w4.y * __builtin_amdgcn_rcpf(ea.y * qc.y + 1.f);
            s1 += w4.z * __builtin_amdgcn_rcpf(ea.z * qc.z + 1.f);
            s1 += w4.w * __builtin_amdgcn_rcpf(ea.w * qc.w + 1.f);
        }
    }

    const float base = *b_o_p + redS[0] + redS[1] + redS[2] + redS[3];
    const int c = c0 + cl;
    const float mk = mask[b * CTX_ + c];
    const float e0 = mk * __expf(base - 2.f * s0);
    const float e1 = mk * __expf(base - 2.f * s1);
    const int qa_ = b * NQ_ + qg * 8 + qi * 2;
    eout[(size_t)qa_ * CTX_ + c]       = e0;
    eout[(size_t)(qa_ + 1) * CTX_ + c] = e1;
    // transposed copy for out_kernel's scalar loads
    *(float2*)&eoutT[(((size_t)(b * 8 + qg) * CTX_) + c) * 8 + qi * 2] =
        make_float2(e0, e1);
}

// ---------------------------------------------------------------------------
// Kernel 3: softmax denom (reference-exact: denom = sum + EPS) + weighted
// context sum. Grid 512 = b(8) x qgroup(8: 8q) x dq(8: 64d).
// Phase 2 reads the 8 per-c e-values via wave-uniform s_loads from eoutT
// (SMEM pipe, zero LDS), accumulates raw sum, multiplies by inv[q] at the end.
// ---------------------------------------------------------------------------
__global__ __launch_bounds__(256) void out_kernel(
    const float* __restrict__ eout,    // B*NQ*CTX
    const float* __restrict__ eoutT,   // (B*8)*CTX*8
    const float* __restrict__ context, // B*CTX*DC
    float* __restrict__ out,           // B*NQ*DC
    float* __restrict__ wout)          // B*NQ*CTX
{
    __shared__ float invs[8];
    __shared__ float pc[3][64][8];     // raw partial sums: 6 KB

    const int blk = blockIdx.x;
    const int b  = blk & 7;
    const int qg = (blk >> 3) & 7;
    const int dq = blk >> 6;           // 0..7: d in [dq*64, +64)
    const int t  = threadIdx.x;

    // Phase 1: denominators for the 8 q (+ wout when dq==0)
    {
        const int qi = t >> 5;         // 0..7
        const int cl = t & 31;
        const int q = b * NQ_ + qg * 8 + qi;
        const float* erow = eout + (size_t)q * CTX_;
        float ev[16];
        float part = 0.f;
        #pragma unroll
        for (int k = 0; k < 16; ++k) { ev[k] = erow[cl + 32 * k]; part += ev[k]; }
        part += __shfl_xor(part, 1);  part += __shfl_xor(part, 2);
        part += __shfl_xor(part, 4);  part += __shfl_xor(part, 8);
        part += __shfl_xor(part, 16);
        const float inv = 1.f / (part + EPS_);
        if (cl == 0) invs[qi] = inv;
        if (dq == 0) {
            #pragma unroll
            for (int k = 0; k < 16; ++k)
                wout[(size_t)q * CTX_ + cl + 32 * k] = ev[k] * inv;
        }
    }
    __syncthreads();

    // Phase 2: raw weighted sum; cq4 = c-quarter (uniform), dt = d-lane
    const int cq4 = __builtin_amdgcn_readfirstlane(t >> 6);   // 0..3, uniform
    const int dt  = t & 63;
    const int d   = dq * 64 + dt;
    const float* cb  = context + ((size_t)(b * CTX_) + cq4 * 128) * DC_ + d;
    const float* eoT = eoutT + (((size_t)(b * 8 + qg) * CTX_) + cq4 * 128) * 8;

    float a0=0,a1=0,a2=0,a3=0,a4=0,a5=0,a6=0,a7=0;
    #pragma unroll 4
    for (int c = 0; c < 128; ++c) {
        const float4 eA = *(const float4*)(eoT + c * 8);      // s_load (uniform)
        const float4 eB = *(const float4*)(eoT + c * 8 + 4);  // s_load (uniform)
        const float v = cb[(size_t)c * DC_];
        a0 += eA.x * v; a1 += eA.y * v; a2 += eA.z * v; a3 += eA.w * v;
        a4 += eB.x * v; a5 += eB.y * v; a6 += eB.z * v; a7 += eB.w * v;
    }
    if (cq4) {
        float* p = pc[cq4 - 1][dt];
        p[0]=a0; p[1]=a1; p[2]=a2; p[3]=a3; p[4]=a4; p[5]=a5; p[6]=a6; p[7]=a7;
    }
    __syncthreads();
    if (cq4 == 0) {
        float r[8] = {a0,a1,a2,a3,a4,a5,a6,a7};
        const int qbase = b * NQ_ + qg * 8;
        #pragma unroll
        for (int j = 0; j < 8; ++j) {
            r[j] = (r[j] + pc[0][dt][j] + pc[1][dt][j] + pc[2][dt][j]) * invs[j];
            out[(size_t)(qbase + j) * DC_ + d] = r[j];
        }
    }
}

extern "C" void kernel_launch(void* const* d_in, const int* in_sizes, int n_in,
                              void* d_out, int out_size, void* d_ws, size_t ws_size,
                              hipStream_t stream) {
    const float* query   = (const float*)d_in[0];  // B,NQ,DQ
    const float* context = (const float*)d_in[1];  // B,CTX,DC
    const float* mask    = (const float*)d_in[2];  // B,CTX
    const float* W_c     = (const float*)d_in[3];  // H,DC
    const float* b_c     = (const float*)d_in[4];  // H
    const float* W_q     = (const float*)d_in[5];  // H,DQ
    const float* W_o     = (const float*)d_in[6];  // H
    const float* b_o     = (const float*)d_in[7];  // scalar

    float* out  = (float*)d_out;                   // B,NQ,DC
    float* wout = out + (size_t)B_ * NQ_ * DC_;    // B,NQ,CTX

    float* Ec    = (float*)d_ws;                       // 4 MB: exp(2*res_c)
    float* Eq    = Ec + (size_t)B_ * CTX_ * H_;        // 512 KB: exp(2*res_q)
    float* eout  = Eq + (size_t)B_ * NQ_ * H_;         // 1 MB: mask*exp(logit)
    float* eoutT = eout + (size_t)B_ * NQ_ * CTX_;     // 1 MB: transposed copy

    gemm_exp<<<dim3(144, 4), 256, 0, stream>>>(
        context, query, W_c, b_c, W_q, Ec, Eq);
    score_kernel<<<512, 256, 0, stream>>>(
        Ec, Eq, W_o, b_o, mask, eout, eoutT);
    out_kernel<<<512, 256, 0, stream>>>(
        eout, eoutT, context, out, wout);
}